// Round 4
// baseline (173.051 us; speedup 1.0000x reference)
//
#include <hip/hip_runtime.h>

typedef unsigned short u16;
typedef __bf16 bf16x8 __attribute__((ext_vector_type(8)));
typedef float f32x4 __attribute__((ext_vector_type(4)));
typedef float f32x16 __attribute__((ext_vector_type(16)));

static __device__ __forceinline__ u16 f2bf(float f) {
  unsigned u = __builtin_bit_cast(unsigned, f);
  u += 0x7fffu + ((u >> 16) & 1u);
  return (u16)(u >> 16);
}
static __device__ __forceinline__ float bf2f(u16 u) {
  return __builtin_bit_cast(float, (unsigned)u << 16);
}
static __device__ __forceinline__ unsigned pk2bf(float a, float b) {
  return (unsigned)f2bf(a) | ((unsigned)f2bf(b) << 16);
}

static __device__ __forceinline__ void gload_lds16(const void* g, void* l) {
  __builtin_amdgcn_global_load_lds((const __attribute__((address_space(1))) unsigned int*)g,
                                   (__attribute__((address_space(3))) unsigned int*)l,
                                   16, 0, 0);
}

// ---------------------------------------------------------------------------
// fp32 -> bf16 conversion for X, Wq, Wk, Wv, Wo (one launch)
// ---------------------------------------------------------------------------
__global__ __launch_bounds__(256) void cvt_all(
    const float* __restrict__ X, const float* __restrict__ Wq, const float* __restrict__ Wk,
    const float* __restrict__ Wv, const float* __restrict__ Wo,
    u16* __restrict__ oX, u16* __restrict__ oWq, u16* __restrict__ oWk,
    u16* __restrict__ oWv, u16* __restrict__ oWo) {
  const int b = blockIdx.x;
  const float* s; u16* d; int lb;
  if (b < 1024)      { s = X;  d = oX;  lb = b; }
  else if (b < 2048) { s = Wq; d = oWq; lb = b - 1024; }
  else if (b < 2304) { s = Wk; d = oWk; lb = b - 2048; }
  else if (b < 2560) { s = Wv; d = oWv; lb = b - 2304; }
  else               { s = Wo; d = oWo; lb = b - 2560; }
  const int base = lb * 4096 + threadIdx.x * 4;
#pragma unroll
  for (int j = 0; j < 4; ++j) {
    const int off = base + j * 1024;
    float4 v = *(const float4*)(s + off);
    ushort4 u;
    u.x = f2bf(v.x); u.y = f2bf(v.y); u.z = f2bf(v.z); u.w = f2bf(v.w);
    *(ushort4*)(d + off) = u;
  }
}

// ---------------------------------------------------------------------------
// Fused QKV GEMM over virtual N=3072: [Wq | Wk | Wv], 128x128 tiles, BK=64.
// ---------------------------------------------------------------------------
__global__ __launch_bounds__(256) void gemm_qkv(
    const u16* __restrict__ A, const u16* __restrict__ Bq, const u16* __restrict__ Bk,
    const u16* __restrict__ Bv, u16* __restrict__ Qb, u16* __restrict__ Kb,
    u16* __restrict__ Vt, const float* __restrict__ cosp, const float* __restrict__ sinp) {
  __shared__ u16 As[128 * 64];
  __shared__ u16 Bs[128 * 64];
  const int tid = threadIdx.x;
  const int lane = tid & 63, w = tid >> 6;
  const int wr = w >> 1, wc = w & 1;
  const int lr = lane & 15, lq = lane >> 4;
  const int bm = blockIdx.y << 7;
  const int bn = blockIdx.x << 7;
  const int K = 2048;

  const u16* Bp; int nb, region;
  if (bn < 2048)      { Bp = Bq; nb = bn;        region = 0; }
  else if (bn < 2560) { Bp = Bk; nb = bn - 2048; region = 1; }
  else                { Bp = Bv; nb = bn - 2560; region = 2; }

  f32x4 acc[4][4] = {};

  for (int kt = 0; kt < 32; ++kt) {
    const int k0 = kt << 6;
#pragma unroll
    for (int i = 0; i < 4; ++i) {
      const int seg = (i << 2) + w;
      const int idx = (seg << 6) + lane;
      const int r = idx >> 3, c = idx & 7;
      const int cs = (c ^ (r & 7)) << 3;
      gload_lds16(A + (size_t)(bm + r) * K + k0 + cs, (char*)As + seg * 1024);
      gload_lds16(Bp + (size_t)(nb + r) * K + k0 + cs, (char*)Bs + seg * 1024);
    }
    __syncthreads();
    bf16x8 af[2][4], bfv[2][4];
#pragma unroll
    for (int ks = 0; ks < 2; ++ks) {
#pragma unroll
      for (int f = 0; f < 4; ++f) {
        const int ra = wr * 64 + f * 16 + lr;
        const int ca = (lq + (ks << 2)) ^ (ra & 7);
        af[ks][f] = *(const bf16x8*)&As[((ra << 3) | ca) << 3];
        const int rb = wc * 64 + f * 16 + lr;
        const int cb = (lq + (ks << 2)) ^ (rb & 7);
        bfv[ks][f] = *(const bf16x8*)&Bs[((rb << 3) | cb) << 3];
      }
    }
#pragma unroll
    for (int ks = 0; ks < 2; ++ks)
#pragma unroll
      for (int mf = 0; mf < 4; ++mf)
#pragma unroll
        for (int nf = 0; nf < 4; ++nf)
          acc[mf][nf] = __builtin_amdgcn_mfma_f32_16x16x32_bf16(
              af[ks][mf], bfv[ks][nf], acc[mf][nf], 0, 0, 0);
    __syncthreads();
  }

  const int rbase = bm + wr * 64;
  const int cb64 = nb + wc * 64;
  if (region == 2) {
    const int hkv = cb64 >> 6;
#pragma unroll
    for (int mf = 0; mf < 4; ++mf) {
      const int s0 = rbase + mf * 16 + lq * 4;
#pragma unroll
      for (int nf = 0; nf < 4; ++nf) {
        const int d = (cb64 & 63) + nf * 16 + lr;
        ushort4 st;
        st.x = f2bf(acc[mf][nf][0]); st.y = f2bf(acc[mf][nf][1]);
        st.z = f2bf(acc[mf][nf][2]); st.w = f2bf(acc[mf][nf][3]);
        *(ushort4*)&Vt[(size_t)hkv * 131072 + (size_t)d * 2048 + s0] = st;
      }
    }
  } else {
    u16* outp = region ? Kb : Qb;
    const int ldo = region ? 512 : 2048;
    const float post = region ? 1.0f : 0.125f;
#pragma unroll
    for (int mf = 0; mf < 4; ++mf)
#pragma unroll
      for (int r = 0; r < 4; ++r) {
        const int s = rbase + mf * 16 + lq * 4 + r;
        const float* cr = cosp + s * 64;
        const float* sr = sinp + s * 64;
#pragma unroll
        for (int nf = 0; nf < 2; ++nf) {
          const int d1 = nf * 16 + lr, d2 = d1 + 32;
          const float x1 = acc[mf][nf][r], x2 = acc[mf][nf + 2][r];
          const float y1 = (x1 * cr[d1] - x2 * sr[d1]) * post;
          const float y2 = (x2 * cr[d2] + x1 * sr[d2]) * post;
          outp[(size_t)s * ldo + cb64 + d1] = f2bf(y1);
          outp[(size_t)s * ldo + cb64 + d2] = f2bf(y2);
        }
      }
  }
}

// ---------------------------------------------------------------------------
// out-proj GEMM (bf16 in, f32 out), 128x128 tile
// ---------------------------------------------------------------------------
__global__ __launch_bounds__(256) void gemm_out(
    const u16* __restrict__ A, const u16* __restrict__ B, float* __restrict__ C,
    int M, int N, int K) {
  __shared__ u16 As[128 * 64];
  __shared__ u16 Bs[128 * 64];
  const int tid = threadIdx.x;
  const int lane = tid & 63, w = tid >> 6;
  const int wr = w >> 1, wc = w & 1;
  const int lr = lane & 15, lq = lane >> 4;
  const int bm = blockIdx.y << 7, bn = blockIdx.x << 7;

  f32x4 acc[4][4] = {};
  const int nK = K >> 6;
  for (int kt = 0; kt < nK; ++kt) {
    const int k0 = kt << 6;
#pragma unroll
    for (int i = 0; i < 4; ++i) {
      const int seg = (i << 2) + w;
      const int idx = (seg << 6) + lane;
      const int r = idx >> 3, c = idx & 7;
      const int cs = (c ^ (r & 7)) << 3;
      gload_lds16(A + (size_t)(bm + r) * K + k0 + cs, (char*)As + seg * 1024);
      gload_lds16(B + (size_t)(bn + r) * K + k0 + cs, (char*)Bs + seg * 1024);
    }
    __syncthreads();
    bf16x8 af[2][4], bfv[2][4];
#pragma unroll
    for (int ks = 0; ks < 2; ++ks) {
#pragma unroll
      for (int f = 0; f < 4; ++f) {
        const int ra = wr * 64 + f * 16 + lr;
        const int ca = (lq + (ks << 2)) ^ (ra & 7);
        af[ks][f] = *(const bf16x8*)&As[((ra << 3) | ca) << 3];
        const int rb = wc * 64 + f * 16 + lr;
        const int cb = (lq + (ks << 2)) ^ (rb & 7);
        bfv[ks][f] = *(const bf16x8*)&Bs[((rb << 3) | cb) << 3];
      }
    }
#pragma unroll
    for (int ks = 0; ks < 2; ++ks)
#pragma unroll
      for (int mf = 0; mf < 4; ++mf)
#pragma unroll
        for (int nf = 0; nf < 4; ++nf)
          acc[mf][nf] = __builtin_amdgcn_mfma_f32_16x16x32_bf16(
              af[ks][mf], bfv[ks][nf], acc[mf][nf], 0, 0, 0);
    __syncthreads();
  }
  const int rbase = bm + wr * 64;
  const int cbase = bn + wc * 64;
#pragma unroll
  for (int mf = 0; mf < 4; ++mf)
#pragma unroll
    for (int r = 0; r < 4; ++r) {
      const int s = rbase + mf * 16 + lq * 4 + r;
#pragma unroll
      for (int nf = 0; nf < 4; ++nf)
        C[(size_t)s * N + cbase + nf * 16 + lr] = acc[mf][nf][r];
    }
}

// ---------------------------------------------------------------------------
// Attention v3: split-KV (grid.z = 2 chunks), KV tile = 32, K prefetched one
// tile ahead (ping-pong regs), V issued early. Unnormalized bf16 partials +
// (m,l) f32, merged by attn_merge. No LDS, no barriers.
// ---------------------------------------------------------------------------
__global__ __launch_bounds__(256, 4) void attn_v3(
    const u16* __restrict__ Qb, const u16* __restrict__ Kb,
    const u16* __restrict__ Vt, u16* __restrict__ P0, u16* __restrict__ P1,
    float* __restrict__ ml) {
  const int hkv = blockIdx.y;
  const int qb = (hkv & 4) ? (63 - (int)blockIdx.x) : (int)blockIdx.x;
  const int chunk = blockIdx.z;
  const int w = threadIdx.x >> 6, lane = threadIdx.x & 63;
  const int col = lane & 31, hi = lane >> 5;
  const int g = col >> 3, r = col & 7;
  const int q0w = qb * 32 + w * 8;
  const int qg = q0w + r;
  const int h = hkv * 4 + g;

  const int nt = qb + 1;            // 32-kv tiles for this q block
  const int half = nt >> 1;
  const int t0 = chunk ? half : 0;
  const int t1 = chunk ? nt : half;

  const u16* qp = Qb + (size_t)qg * 2048 + h * 64 + hi * 8;
  uint4 qf[4];
#pragma unroll
  for (int s = 0; s < 4; ++s) qf[s] = *(const uint4*)(qp + 16 * s);

  const u16* Kp = Kb + (size_t)col * 512 + hkv * 64 + hi * 8;
  const u16* Vp = Vt + (size_t)hkv * 131072 + (size_t)col * 2048 + hi * 8;

  f32x16 o0 = {}, o1 = {};
  float m = -1e30f, l = 0.f;

  uint4 ka[4], kb_[4];

  auto loadK = [&](uint4 (&dst)[4], int t) {
    const u16* p = Kp + (size_t)(t << 5) * 512;
#pragma unroll
    for (int s = 0; s < 4; ++s) dst[s] = *(const uint4*)(p + 16 * s);  // +16s along d
  };

  auto body = [&](uint4 (&cur)[4], uint4 (&nxt)[4], int t) {
    const int kv0 = t << 5;
    // issue V loads for this tile (needed after softmax)
    uint4 vf[4];
#pragma unroll
    for (int dt = 0; dt < 2; ++dt)
#pragma unroll
      for (int s = 0; s < 2; ++s)
        vf[dt * 2 + s] = *(const uint4*)(Vp + (size_t)dt * 65536 + kv0 + 16 * s);
    // prefetch K for next tile
    if (t + 1 < t1) loadK(nxt, t + 1);

    f32x16 sc = {};
#pragma unroll
    for (int s = 0; s < 4; ++s)
      sc = __builtin_amdgcn_mfma_f32_32x32x16_bf16(
          __builtin_bit_cast(bf16x8, cur[s]), __builtin_bit_cast(bf16x8, qf[s]), sc, 0, 0, 0);

    if (t == nt - 1) {  // diagonal tile mask
      const int qoff = w * 8 + r;
#pragma unroll
      for (int i = 0; i < 16; ++i) {
        const int kvr = (i & 3) + 8 * (i >> 2) + 4 * hi;
        if (kvr > qoff) sc[i] = -1e30f;
      }
    }

    float pa = fmaxf(fmaxf(sc[0], sc[1]), fmaxf(sc[2], sc[3]));
    float pb = fmaxf(fmaxf(sc[4], sc[5]), fmaxf(sc[6], sc[7]));
    float pc = fmaxf(fmaxf(sc[8], sc[9]), fmaxf(sc[10], sc[11]));
    float pd = fmaxf(fmaxf(sc[12], sc[13]), fmaxf(sc[14], sc[15]));
    float pm = fmaxf(fmaxf(pa, pb), fmaxf(pc, pd));
    pm = fmaxf(pm, __shfl_xor(pm, 32, 64));

    if (!__all(pm - m <= 8.0f)) {
      const float mn = fmaxf(m, pm);
      const float al = __expf(m - mn);
      m = mn; l *= al;
#pragma unroll
      for (int i = 0; i < 16; ++i) { o0[i] *= al; o1[i] *= al; }
    }

    float p[16];
    float r0 = 0.f, r1 = 0.f, r2 = 0.f, r3 = 0.f;
#pragma unroll
    for (int i = 0; i < 4; ++i) {
      p[4 * i]     = __expf(sc[4 * i]     - m); r0 += p[4 * i];
      p[4 * i + 1] = __expf(sc[4 * i + 1] - m); r1 += p[4 * i + 1];
      p[4 * i + 2] = __expf(sc[4 * i + 2] - m); r2 += p[4 * i + 2];
      p[4 * i + 3] = __expf(sc[4 * i + 3] - m); r3 += p[4 * i + 3];
    }
    float rs = (r0 + r1) + (r2 + r3);
    l += rs + __shfl_xor(rs, 32, 64);

    unsigned W0[4], W1[4];
#pragma unroll
    for (int gg = 0; gg < 4; ++gg) {
      W0[gg] = pk2bf(p[4 * gg], p[4 * gg + 1]);
      W1[gg] = pk2bf(p[4 * gg + 2], p[4 * gg + 3]);
    }
#pragma unroll
    for (int G = 0; G < 2; ++G) {
      const int ga = 2 * G, gb = 2 * G + 1;
      const unsigned x0 = __shfl_xor(W0[gb], 32, 64);
      const unsigned x1 = __shfl_xor(W1[gb], 32, 64);
      const unsigned x2 = __shfl_xor(W0[ga], 32, 64);
      const unsigned x3 = __shfl_xor(W1[ga], 32, 64);
      uint4 pw;
      pw.x = hi ? x0 : W0[ga];
      pw.y = hi ? x1 : W1[ga];
      pw.z = hi ? W0[gb] : x2;
      pw.w = hi ? W1[gb] : x3;
      const bf16x8 pf = __builtin_bit_cast(bf16x8, pw);
      o0 = __builtin_amdgcn_mfma_f32_32x32x16_bf16(
          __builtin_bit_cast(bf16x8, vf[G]), pf, o0, 0, 0, 0);
      o1 = __builtin_amdgcn_mfma_f32_32x32x16_bf16(
          __builtin_bit_cast(bf16x8, vf[2 + G]), pf, o1, 0, 0, 0);
    }
  };

  int t = t0;
  if (t < t1) {
    loadK(ka, t);
    while (true) {
      body(ka, kb_, t); ++t; if (t >= t1) break;
      body(kb_, ka, t); ++t; if (t >= t1) break;
    }
  }

  // store unnormalized partials
  u16* Pc = chunk ? P1 : P0;
  u16* op = Pc + (size_t)qg * 2048 + h * 64;
#pragma unroll
  for (int gg = 0; gg < 4; ++gg) {
    ushort4 s0, s1;
    s0.x = f2bf(o0[4 * gg]);     s0.y = f2bf(o0[4 * gg + 1]);
    s0.z = f2bf(o0[4 * gg + 2]); s0.w = f2bf(o0[4 * gg + 3]);
    s1.x = f2bf(o1[4 * gg]);     s1.y = f2bf(o1[4 * gg + 1]);
    s1.z = f2bf(o1[4 * gg + 2]); s1.w = f2bf(o1[4 * gg + 3]);
    *(ushort4*)(op + 8 * gg + 4 * hi)      = s0;
    *(ushort4*)(op + 8 * gg + 4 * hi + 32) = s1;
  }
  if (hi == 0) {
    float* mlw = ml + (((size_t)chunk * 2048 + qg) * 32 + h) * 2;
    mlw[0] = m; mlw[1] = l;
  }
}

// ---------------------------------------------------------------------------
// merge the two KV-chunk partials -> ctx bf16
// ---------------------------------------------------------------------------
__global__ __launch_bounds__(256) void attn_merge(
    const u16* __restrict__ P0, const u16* __restrict__ P1,
    const float* __restrict__ ml, u16* __restrict__ Cx) {
  const int s = blockIdx.x;
  const int e0 = threadIdx.x * 8;
  const int h = e0 >> 6;
  const float* mp = ml + ((size_t)s * 32 + h) * 2;
  const float m0 = mp[0], l0 = mp[1];
  const float m1 = mp[131072], l1 = mp[131073];
  const float M = fmaxf(m0, m1);
  float w0 = __expf(m0 - M), w1 = __expf(m1 - M);
  const float inv = 1.f / (l0 * w0 + l1 * w1);
  w0 *= inv; w1 *= inv;
  uint4 a = *(const uint4*)(P0 + (size_t)s * 2048 + e0);
  uint4 b = *(const uint4*)(P1 + (size_t)s * 2048 + e0);
  const u16* pa = (const u16*)&a;
  const u16* pb = (const u16*)&b;
  ushort4 oA, oB;
  oA.x = f2bf(bf2f(pa[0]) * w0 + bf2f(pb[0]) * w1);
  oA.y = f2bf(bf2f(pa[1]) * w0 + bf2f(pb[1]) * w1);
  oA.z = f2bf(bf2f(pa[2]) * w0 + bf2f(pb[2]) * w1);
  oA.w = f2bf(bf2f(pa[3]) * w0 + bf2f(pb[3]) * w1);
  oB.x = f2bf(bf2f(pa[4]) * w0 + bf2f(pb[4]) * w1);
  oB.y = f2bf(bf2f(pa[5]) * w0 + bf2f(pb[5]) * w1);
  oB.z = f2bf(bf2f(pa[6]) * w0 + bf2f(pb[6]) * w1);
  oB.w = f2bf(bf2f(pa[7]) * w0 + bf2f(pb[7]) * w1);
  *(ushort4*)(Cx + (size_t)s * 2048 + e0)     = oA;
  *(ushort4*)(Cx + (size_t)s * 2048 + e0 + 4) = oB;
}

// ---------------------------------------------------------------------------
extern "C" void kernel_launch(void* const* d_in, const int* in_sizes, int n_in,
                              void* d_out, int out_size, void* d_ws, size_t ws_size,
                              hipStream_t stream) {
  const float* X    = (const float*)d_in[0];
  const float* cosp = (const float*)d_in[1];
  const float* sinp = (const float*)d_in[2];
  const float* Wq   = (const float*)d_in[3];
  const float* Wk   = (const float*)d_in[4];
  const float* Wv   = (const float*)d_in[5];
  const float* Wo   = (const float*)d_in[6];

  u16* ws  = (u16*)d_ws;
  u16* Xb  = ws;                         // 2048x2048 (later reused as P0)
  u16* Wqb = ws + 4194304;               // 2048x2048 (later reused as P1)
  u16* Wkb = ws + 8388608;               // 512x2048  (later reused as ml)
  u16* Wvb = ws + 9437184;               // 512x2048
  u16* Wob = ws + 10485760;              // 2048x2048
  u16* Qb  = ws + 14680064;              // 2048x2048 (rope'd * 1/8)
  u16* Kb  = ws + 18874368;              // 2048x512  (rope'd)
  u16* Vt  = ws + 19922944;              // 8x64x2048 (V transposed per head)
  u16* Cx  = ws + 20971520;              // 2048x2048 ctx
  u16* P0  = Xb;
  u16* P1  = Wqb;
  float* ml = (float*)(ws + 8388608);

  cvt_all<<<3584, 256, 0, stream>>>(X, Wq, Wk, Wv, Wo, Xb, Wqb, Wkb, Wvb, Wob);

  dim3 gqkv(24, 16), ga(64, 8, 2), go(16, 16);
  gemm_qkv<<<gqkv, 256, 0, stream>>>(Xb, Wqb, Wkb, Wvb, Qb, Kb, Vt, cosp, sinp);
  attn_v3<<<ga, 256, 0, stream>>>(Qb, Kb, Vt, P0, P1, ml);
  attn_merge<<<2048, 256, 0, stream>>>(P0, P1, ml, Cx);
  gemm_out<<<go, 256, 0, stream>>>(Cx, Wob, (float*)d_out, 2048, 2048, 2048);
}